// Round 1
// baseline (905.890 us; speedup 1.0000x reference)
//
#include <hip/hip_runtime.h>
#include <cstdint>

#define B   64
#define NJ  21
#define CHN 256
#define HW  4096
#define G3  768

// ---------- Laplacian: L = I - D^-1/2 A D^-1/2 ----------
__global__ __launch_bounds__(64) void k_lap(const float* __restrict__ adj, float* __restrict__ L){
  __shared__ float dinv[NJ];
  int t = threadIdx.x;
  if (t < NJ){
    float s = 0.f;
    for (int j=0;j<NJ;j++) s += adj[t*NJ+j];
    dinv[t] = s > 0.f ? 1.f/sqrtf(s) : 0.f;
  }
  __syncthreads();
  for (int idx=t; idx<NJ*NJ; idx+=64){
    int i = idx/NJ, j = idx%NJ;
    L[idx] = (i==j ? 1.f : 0.f) - dinv[i]*adj[idx]*dinv[j];
  }
}

// ---------- Correlation: q[b,j,c] = sum_p T[b,j,p] * F[b,c,p] ----------
// grid 1024 = 16 cq x 64 b (b in low bits so all blocks of one b share an XCD-L2 for T)
// block 256: wave w (4), lane l: pl = l&15 (p-slice), cg = l>>4 ; c = cq*16 + w*4 + cg
__global__ __launch_bounds__(256,4) void k_corr(const float* __restrict__ T,
    const float* __restrict__ F, float* __restrict__ q){
  int cq = blockIdx.x >> 6, b = blockIdx.x & 63;
  int t = threadIdx.x;
  int wv = t >> 6, l = t & 63;
  int pl = l & 15, cg = l >> 4;
  int c = cq*16 + wv*4 + cg;
  const float4* Fp = (const float4*)(F + ((size_t)b*CHN + c)*HW);
  const float4* Tp = (const float4*)(T + (size_t)b*NJ*HW);
  float acc[NJ];
  #pragma unroll
  for (int j=0;j<NJ;j++) acc[j] = 0.f;
  for (int it=0; it<64; ++it){
    int p4 = it*16 + pl;               // float4 index; lanes 0..15 contiguous -> coalesced
    float4 f4 = Fp[p4];
    #pragma unroll
    for (int j=0;j<NJ;j++){
      float4 t4 = Tp[j*1024 + p4];
      acc[j] += t4.x*f4.x; acc[j] += t4.y*f4.y;
      acc[j] += t4.z*f4.z; acc[j] += t4.w*f4.w;
    }
  }
  #pragma unroll
  for (int j=0;j<NJ;j++){
    float v = acc[j];
    v += __shfl_xor(v,1); v += __shfl_xor(v,2);
    v += __shfl_xor(v,4); v += __shfl_xor(v,8);
    acc[j] = v;
  }
  if (pl == 0){
    #pragma unroll
    for (int j=0;j<NJ;j++) q[((size_t)b*NJ + j)*CHN + c] = acc[j];
  }
}

// ---------- BN stats per joint over (b, c): 16384 values ----------
__global__ __launch_bounds__(256) void k_stats(const float* __restrict__ q, float* __restrict__ stats){
  int j = blockIdx.x, t = threadIdx.x;
  float s = 0.f, ss = 0.f;
  for (int b=0;b<B;b++){
    float v = q[((size_t)b*NJ + j)*CHN + t];
    s += v; ss += v*v;
  }
  #pragma unroll
  for (int o=32;o>0;o>>=1){ s += __shfl_down(s,o); ss += __shfl_down(ss,o); }
  __shared__ float sb[4], ssb[4];
  int wid = t>>6;
  if ((t&63)==0){ sb[wid]=s; ssb[wid]=ss; }
  __syncthreads();
  if (t==0){
    float S  = sb[0]+sb[1]+sb[2]+sb[3];
    float SS = ssb[0]+ssb[1]+ssb[2]+ssb[3];
    float mean = S * (1.f/16384.f);
    float var  = SS * (1.f/16384.f) - mean*mean;
    stats[j]      = mean;
    stats[NJ + j] = 1.f/sqrtf(var + 1e-5f);
  }
}

// ---------- BN apply + LeakyReLU + xg = xn @ wx + bx ----------
// grid 192 = 64 b x 3 col-slices of 256; thread owns one output column
__global__ __launch_bounds__(256) void k_xg(const float* __restrict__ q,
    const float* __restrict__ stats, const float* __restrict__ gamma, const float* __restrict__ beta,
    const float* __restrict__ wx, const float* __restrict__ bx, float* __restrict__ xg){
  int b = blockIdx.x/3, sl = blockIdx.x%3;
  int t = threadIdx.x;
  int col = sl*256 + t;
  __shared__ float xn[NJ][CHN];
  for (int idx=t; idx<NJ*CHN; idx+=256){
    int j = idx >> 8;
    float v = (q[(size_t)b*NJ*CHN + idx] - stats[j]) * stats[NJ+j];
    v = v * gamma[j] + beta[j];
    xn[j][idx & 255] = v > 0.f ? v : 0.1f*v;
  }
  __syncthreads();
  float acc[NJ];
  #pragma unroll
  for (int j=0;j<NJ;j++) acc[j]=0.f;
  for (int c=0;c<CHN;c++){
    float wv = wx[(size_t)c*G3 + col];          // coalesced across threads
    #pragma unroll
    for (int j=0;j<NJ;j++) acc[j] += xn[j][c]*wv;   // xn broadcast
  }
  float bv = bx[col];
  #pragma unroll
  for (int j=0;j<NJ;j++) xg[((size_t)b*NJ+j)*G3 + col] = acc[j] + bv;
}

// ---------- Persistent GRU: 512 blocks = 64 batches x 8 hidden-slices ----------
// block 384 thr = 96 cols (3 gates x 32 hidden) x 4 c-quarters; wh held in VGPRs.
// Cross-block h exchange via agent-scope atomics + monotonic counter, double-buffered h.
__global__ __launch_bounds__(384,3) void k_gru(const float* __restrict__ xg,
    const float* __restrict__ wh, const float* __restrict__ bh,
    float* __restrict__ hbuf, unsigned int* __restrict__ cnt, float* __restrict__ gout){
  int b = blockIdx.x >> 3, s = blockIdx.x & 7;
  int t = threadIdx.x;
  int cl = t >> 2, ch = t & 3;          // cl: which column, ch: which c-quarter (64 c each)
  int gate = cl >> 5, il = cl & 31;
  int ig  = s*32 + il;                  // hidden index
  int col = gate*256 + ig;              // column in [0,768)
  __shared__ __align__(16) float hl[256];
  __shared__ float lr[32], lz[32];
  float w[64];
  #pragma unroll
  for (int k=0;k<64;k++) w[k] = wh[(size_t)(ch*64+k)*G3 + col];
  float bhv = bh[col];
  if (t < 256) hl[t] = 0.f;             // h0 = 0
  __syncthreads();
  const float4* hl4 = (const float4*)hl;
  for (int step=0; step<NJ; ++step){
    float hg = 0.f;
    #pragma unroll
    for (int k4=0;k4<16;k4++){
      float4 hv = hl4[ch*16+k4];        // uniform per quarter -> LDS broadcast
      hg += w[4*k4+0]*hv.x; hg += w[4*k4+1]*hv.y;
      hg += w[4*k4+2]*hv.z; hg += w[4*k4+3]*hv.w;
    }
    hg += __shfl_xor(hg,1);
    hg += __shfl_xor(hg,2);             // full dot over 256 c
    hg += bhv;
    float xv = xg[((size_t)b*NJ + step)*G3 + col];
    if (ch==0){
      if (gate==0)      lr[il] = 1.f/(1.f+__expf(-(xv+hg)));
      else if (gate==1) lz[il] = 1.f/(1.f+__expf(-(xv+hg)));
    }
    __syncthreads();
    int nxt = (step+1)&1;
    if (gate==2 && ch==0){
      float nv = tanhf(xv + lr[il]*hg);
      float zv = lz[il];
      float hnew = (1.f-zv)*nv + zv*hl[ig];
      gout[((size_t)b*NJ+step)*CHN + ig] = hnew;
      __hip_atomic_store(&hbuf[(size_t)nxt*(B*CHN) + b*CHN + ig], hnew,
                         __ATOMIC_RELAXED, __HIP_MEMORY_SCOPE_AGENT);
    }
    __syncthreads();                    // drains stores (vmcnt0) before counting
    if (step == NJ-1) break;
    if (t==0){
      __hip_atomic_fetch_add(&cnt[b], 1u, __ATOMIC_RELEASE, __HIP_MEMORY_SCOPE_AGENT);
      unsigned tgt = 8u*(unsigned)(step+1);
      while (__hip_atomic_load(&cnt[b], __ATOMIC_ACQUIRE, __HIP_MEMORY_SCOPE_AGENT) < tgt)
        __builtin_amdgcn_s_sleep(2);
    }
    __syncthreads();
    if (t < 256)
      hl[t] = __hip_atomic_load(&hbuf[(size_t)nxt*(B*CHN) + b*CHN + t],
                                __ATOMIC_RELAXED, __HIP_MEMORY_SCOPE_AGENT);
    __syncthreads();
  }
}

// ---------- ChebConv K=2 + bias + ReLU: out = relu(x@W0 + (Lx)@W1 + b) ----------
// grid 256 = 64 b x 4 out-quarters; thread = (out col in quarter, c-quarter)
__global__ __launch_bounds__(256) void k_cheb(const float* __restrict__ xin,
    const float* __restrict__ Lm, const float* __restrict__ W,
    const float* __restrict__ bvec, float* __restrict__ out){
  int b = blockIdx.x >> 2, oq = blockIdx.x & 3;
  int t = threadIdx.x;
  int ol = t & 63, ck = t >> 6;
  __shared__ float xs[NJ][CHN];
  __shared__ float lx[NJ][CHN];
  __shared__ float part[4][64][NJ];
  for (int idx=t; idx<NJ*CHN; idx+=256) xs[idx>>8][idx&255] = xin[(size_t)b*NJ*CHN + idx];
  __syncthreads();
  for (int idx=t; idx<NJ*CHN; idx+=256){
    int j = idx>>8, c = idx&255;
    float sacc = 0.f;
    #pragma unroll
    for (int m=0;m<NJ;m++) sacc += Lm[j*NJ+m]*xs[m][c];
    lx[j][c] = sacc;
  }
  __syncthreads();
  int o = oq*64 + ol;
  float acc[NJ];
  #pragma unroll
  for (int j=0;j<NJ;j++) acc[j]=0.f;
  const float* W0 = W;
  const float* W1 = W + CHN*CHN;
  for (int cc=0; cc<64; ++cc){
    int c = ck*64 + cc;
    float w0 = W0[(size_t)c*CHN + o];    // coalesced
    float w1 = W1[(size_t)c*CHN + o];
    #pragma unroll
    for (int j=0;j<NJ;j++){ acc[j] += xs[j][c]*w0; acc[j] += lx[j][c]*w1; }
  }
  #pragma unroll
  for (int j=0;j<NJ;j++) part[ck][ol][j] = acc[j];
  __syncthreads();
  for (int idx=t; idx<64*NJ; idx+=256){
    int o2 = idx & 63, j = idx >> 6;
    float s2 = part[0][o2][j]+part[1][o2][j]+part[2][o2][j]+part[3][o2][j] + bvec[oq*64+o2];
    s2 = s2 > 0.f ? s2 : 0.f;
    out[(size_t)b*NJ*CHN + j*CHN + oq*64 + o2] = s2;
  }
}

// ---------- Output head: x = gru_out + h2 ; out = x@W0 + (Lx)@W1 + b  -> [B,21,3] ----------
__global__ __launch_bounds__(64) void k_out(const float* __restrict__ gq, const float* __restrict__ h2,
    const float* __restrict__ Lm, const float* __restrict__ W, const float* __restrict__ bvec,
    float* __restrict__ out){
  int b = blockIdx.x, t = threadIdx.x;
  __shared__ float xs[NJ][CHN];
  __shared__ float lx[NJ][CHN];
  for (int idx=t; idx<NJ*CHN; idx+=64)
    xs[idx>>8][idx&255] = gq[(size_t)b*NJ*CHN+idx] + h2[(size_t)b*NJ*CHN+idx];
  __syncthreads();
  for (int idx=t; idx<NJ*CHN; idx+=64){
    int j = idx>>8, c = idx&255;
    float s = 0.f;
    #pragma unroll
    for (int m=0;m<NJ;m++) s += Lm[j*NJ+m]*xs[m][c];
    lx[j][c] = s;
  }
  __syncthreads();
  if (t < 63){
    int j = t/3, o = t%3;
    float acc = bvec[o];
    const float* W0 = W;
    const float* W1 = W + CHN*3;
    for (int c=0;c<CHN;c++){
      acc += xs[j][c]*W0[c*3+o];
      acc += lx[j][c]*W1[c*3+o];
    }
    out[(size_t)b*63 + t] = acc;
  }
}

extern "C" void kernel_launch(void* const* d_in, const int* in_sizes, int n_in,
                              void* d_out, int out_size, void* d_ws, size_t ws_size,
                              hipStream_t stream){
  const float* feat  = (const float*)d_in[0];
  const float* targ  = (const float*)d_in[1];
  const float* adj   = (const float*)d_in[2];
  const float* gamma = (const float*)d_in[3];
  const float* beta  = (const float*)d_in[4];
  const float* wx    = (const float*)d_in[5];
  const float* wh    = (const float*)d_in[6];
  const float* bx    = (const float*)d_in[7];
  const float* bh    = (const float*)d_in[8];
  const float* wg1   = (const float*)d_in[9];
  const float* bg1   = (const float*)d_in[10];
  const float* wg2   = (const float*)d_in[11];
  const float* bg2   = (const float*)d_in[12];
  const float* wout  = (const float*)d_in[13];
  const float* bout  = (const float*)d_in[14];

  float* ws   = (float*)d_ws;
  float* q     = ws + 0;          // 344064
  float* stats = ws + 344064;     // 64
  float* Lw    = ws + 344128;     // 448
  float* xgw   = ws + 344576;     // 1032192
  float* gout  = ws + 1376768;    // 344064
  float* h1    = ws + 1720832;    // 344064
  float* h2    = ws + 2064896;    // 344064
  float* hbuf  = ws + 2408960;    // 32768 (2 x 64 x 256)
  unsigned int* cnt = (unsigned int*)(ws + 2441728); // 64

  hipMemsetAsync(cnt, 0, 64*sizeof(unsigned int), stream);
  k_lap  <<<1,    64, 0, stream>>>(adj, Lw);
  k_corr <<<1024,256, 0, stream>>>(targ, feat, q);
  k_stats<<<21,  256, 0, stream>>>(q, stats);
  k_xg   <<<192, 256, 0, stream>>>(q, stats, gamma, beta, wx, bx, xgw);
  k_gru  <<<512, 384, 0, stream>>>(xgw, wh, bh, hbuf, cnt, gout);
  k_cheb <<<256, 256, 0, stream>>>(gout, Lw, wg1, bg1, h1);
  k_cheb <<<256, 256, 0, stream>>>(h1,   Lw, wg2, bg2, h2);
  k_out  <<<64,   64, 0, stream>>>(gout, h2, Lw, wout, bout, (float*)d_out);
}

// Round 3
// 393.209 us; speedup vs baseline: 2.3038x; 2.3038x over previous
//
#include <hip/hip_runtime.h>
#include <cstdint>

#define B   64
#define NJ  21
#define CHN 256
#define HW  4096
#define G3  768

typedef _Float16 f16x2 __attribute__((ext_vector_type(2)));
union HU { unsigned u; f16x2 h; };

static __device__ inline unsigned pack_f16(float a, float b){
  HU u; u.h.x = (_Float16)a; u.h.y = (_Float16)b; return u.u;
}

// ---------- Laplacian: L = I - D^-1/2 A D^-1/2 ----------
__global__ __launch_bounds__(64) void k_lap(const float* __restrict__ adj, float* __restrict__ L){
  __shared__ float dinv[NJ];
  int t = threadIdx.x;
  if (t < NJ){
    float s = 0.f;
    for (int j=0;j<NJ;j++) s += adj[t*NJ+j];
    dinv[t] = s > 0.f ? 1.f/sqrtf(s) : 0.f;
  }
  __syncthreads();
  for (int idx=t; idx<NJ*NJ; idx+=64){
    int i = idx/NJ, j = idx%NJ;
    L[idx] = (i==j ? 1.f : 0.f) - dinv[i]*adj[idx]*dinv[j];
  }
}

// ---------- Correlation: q[b,j,c] = sum_p T[b,j,p] * F[b,c,p] ----------
__global__ __launch_bounds__(256,4) void k_corr(const float* __restrict__ T,
    const float* __restrict__ F, float* __restrict__ q){
  int cq = blockIdx.x >> 6, b = blockIdx.x & 63;
  int t = threadIdx.x;
  int wv = t >> 6, l = t & 63;
  int pl = l & 15, cg = l >> 4;
  int c = cq*16 + wv*4 + cg;
  const float4* Fp = (const float4*)(F + ((size_t)b*CHN + c)*HW);
  const float4* Tp = (const float4*)(T + (size_t)b*NJ*HW);
  float acc[NJ];
  #pragma unroll
  for (int j=0;j<NJ;j++) acc[j] = 0.f;
  for (int it=0; it<64; ++it){
    int p4 = it*16 + pl;
    float4 f4 = Fp[p4];
    #pragma unroll
    for (int j=0;j<NJ;j++){
      float4 t4 = Tp[j*1024 + p4];
      acc[j] += t4.x*f4.x; acc[j] += t4.y*f4.y;
      acc[j] += t4.z*f4.z; acc[j] += t4.w*f4.w;
    }
  }
  #pragma unroll
  for (int j=0;j<NJ;j++){
    float v = acc[j];
    v += __shfl_xor(v,1); v += __shfl_xor(v,2);
    v += __shfl_xor(v,4); v += __shfl_xor(v,8);
    acc[j] = v;
  }
  if (pl == 0){
    #pragma unroll
    for (int j=0;j<NJ;j++) q[((size_t)b*NJ + j)*CHN + c] = acc[j];
  }
}

// ---------- BN stats per joint ----------
__global__ __launch_bounds__(256) void k_stats(const float* __restrict__ q, float* __restrict__ stats){
  int j = blockIdx.x, t = threadIdx.x;
  float s = 0.f, ss = 0.f;
  for (int b=0;b<B;b++){
    float v = q[((size_t)b*NJ + j)*CHN + t];
    s += v; ss += v*v;
  }
  #pragma unroll
  for (int o=32;o>0;o>>=1){ s += __shfl_down(s,o); ss += __shfl_down(ss,o); }
  __shared__ float sb[4], ssb[4];
  int wid = t>>6;
  if ((t&63)==0){ sb[wid]=s; ssb[wid]=ss; }
  __syncthreads();
  if (t==0){
    float S  = sb[0]+sb[1]+sb[2]+sb[3];
    float SS = ssb[0]+ssb[1]+ssb[2]+ssb[3];
    float mean = S * (1.f/16384.f);
    float var  = SS * (1.f/16384.f) - mean*mean;
    stats[j]      = mean;
    stats[NJ + j] = 1.f/sqrtf(var + 1e-5f);
  }
}

// ---------- BN apply + LeakyReLU + xg = xn @ wx + bx ----------
__global__ __launch_bounds__(256) void k_xg(const float* __restrict__ q,
    const float* __restrict__ stats, const float* __restrict__ gamma, const float* __restrict__ beta,
    const float* __restrict__ wx, const float* __restrict__ bx, float* __restrict__ xg){
  int b = blockIdx.x/3, sl = blockIdx.x%3;
  int t = threadIdx.x;
  int col = sl*256 + t;
  __shared__ float xn[NJ][CHN];
  for (int idx=t; idx<NJ*CHN; idx+=256){
    int j = idx >> 8;
    float v = (q[(size_t)b*NJ*CHN + idx] - stats[j]) * stats[NJ+j];
    v = v * gamma[j] + beta[j];
    xn[j][idx & 255] = v > 0.f ? v : 0.1f*v;
  }
  __syncthreads();
  float acc[NJ];
  #pragma unroll
  for (int j=0;j<NJ;j++) acc[j]=0.f;
  for (int c=0;c<CHN;c++){
    float wv = wx[(size_t)c*G3 + col];
    #pragma unroll
    for (int j=0;j<NJ;j++) acc[j] += xn[j][c]*wv;
  }
  float bv = bx[col];
  #pragma unroll
  for (int j=0;j<NJ;j++) xg[((size_t)b*NJ+j)*G3 + col] = acc[j] + bv;
}

// ---------- pack wh to f16 pairs: whp[c2][col] = (wh[2c2][col], wh[2c2+1][col]) ----------
__global__ __launch_bounds__(256) void k_pack(const float* __restrict__ wh, unsigned* __restrict__ whp){
  int idx = blockIdx.x*256 + threadIdx.x;   // 128*768 = 98304 -> 384 blocks
  int c2 = idx / G3, col = idx % G3;
  float w0 = wh[(size_t)(2*c2)*G3 + col];
  float w1 = wh[(size_t)(2*c2+1)*G3 + col];
  whp[idx] = pack_f16(w0, w1);
}

// ---------- GRU: one block per batch, no cross-block sync ----------
// 768 threads = output columns. Weights stream from L2 as f16 pairs (384 KB/step).
// h broadcast via v_readlane -> SGPR operand of v_dot2_f32_f16 (no LDS in hot loop).
__global__ __launch_bounds__(768,3) void k_gru(const unsigned* __restrict__ whp,
    const float* __restrict__ bh, const float* __restrict__ xg, float* __restrict__ gout){
  int b = blockIdx.x;
  int col = threadIdx.x;
  int l = col & 63;
  __shared__ float hf[256];
  __shared__ float lr[256], lz[256];
  float bhv = bh[col];
  if (col < 256) hf[col] = 0.f;
  unsigned hv0 = 0u, hv1 = 0u;          // lane l holds h-pairs c2=l and c2=64+l
  float xv_next = xg[((size_t)b*NJ + 0)*G3 + col];
  __syncthreads();
  for (int step=0; step<NJ; ++step){
    float xvc = xv_next;
    if (step < NJ-1) xv_next = xg[((size_t)b*NJ + step+1)*G3 + col];
    float a0 = 0.f, a1 = 0.f;
    #pragma unroll
    for (int c2=0; c2<64; ++c2){
      HU w; w.u = whp[c2*G3 + col];
      HU h; h.u = __builtin_amdgcn_readlane(hv0, c2);
#if __has_builtin(__builtin_amdgcn_fdot2)
      a0 = __builtin_amdgcn_fdot2(w.h, h.h, a0, false);
#else
      a0 += (float)w.h.x*(float)h.h.x + (float)w.h.y*(float)h.h.y;
#endif
    }
    #pragma unroll
    for (int c2=0; c2<64; ++c2){
      HU w; w.u = whp[(64+c2)*G3 + col];
      HU h; h.u = __builtin_amdgcn_readlane(hv1, c2);
#if __has_builtin(__builtin_amdgcn_fdot2)
      a1 = __builtin_amdgcn_fdot2(w.h, h.h, a1, false);
#else
      a1 += (float)w.h.x*(float)h.h.x + (float)w.h.y*(float)h.h.y;
#endif
    }
    float a = a0 + a1 + bhv;
    if (col < 256)      lr[col]     = 1.f/(1.f+__expf(-(xvc + a)));
    else if (col < 512) lz[col-256] = 1.f/(1.f+__expf(-(xvc + a)));
    __syncthreads();
    if (col >= 512){
      int i = col - 512;
      float nv = tanhf(xvc + lr[i]*a);
      float z  = lz[i];
      float hnew = (1.f - z)*nv + z*hf[i];
      gout[((size_t)b*NJ + step)*CHN + i] = hnew;
      hf[i] = hnew;
    }
    __syncthreads();
    // every wave rebuilds its private packed-h registers
    float2 p0 = *(const float2*)&hf[2*l];
    float2 p1 = *(const float2*)&hf[128 + 2*l];
    hv0 = pack_f16(p0.x, p0.y);
    hv1 = pack_f16(p1.x, p1.y);
  }
}

// ---------- ChebConv K=2 + bias + ReLU ----------
__global__ __launch_bounds__(256) void k_cheb(const float* __restrict__ xin,
    const float* __restrict__ Lm, const float* __restrict__ W,
    const float* __restrict__ bvec, float* __restrict__ out){
  int b = blockIdx.x >> 2, oq = blockIdx.x & 3;
  int t = threadIdx.x;
  int ol = t & 63, ck = t >> 6;
  __shared__ float xs[NJ][CHN];
  __shared__ float lx[NJ][CHN];
  __shared__ float part[4][64][NJ];
  for (int idx=t; idx<NJ*CHN; idx+=256) xs[idx>>8][idx&255] = xin[(size_t)b*NJ*CHN + idx];
  __syncthreads();
  for (int idx=t; idx<NJ*CHN; idx+=256){
    int j = idx>>8, c = idx&255;
    float sacc = 0.f;
    #pragma unroll
    for (int m=0;m<NJ;m++) sacc += Lm[j*NJ+m]*xs[m][c];
    lx[j][c] = sacc;
  }
  __syncthreads();
  int o = oq*64 + ol;
  float acc[NJ];
  #pragma unroll
  for (int j=0;j<NJ;j++) acc[j]=0.f;
  const float* W0 = W;
  const float* W1 = W + CHN*CHN;
  for (int cc=0; cc<64; ++cc){
    int c = ck*64 + cc;
    float w0 = W0[(size_t)c*CHN + o];
    float w1 = W1[(size_t)c*CHN + o];
    #pragma unroll
    for (int j=0;j<NJ;j++){ acc[j] += xs[j][c]*w0; acc[j] += lx[j][c]*w1; }
  }
  #pragma unroll
  for (int j=0;j<NJ;j++) part[ck][ol][j] = acc[j];
  __syncthreads();
  for (int idx=t; idx<64*NJ; idx+=256){
    int o2 = idx & 63, j = idx >> 6;
    float s2 = part[0][o2][j]+part[1][o2][j]+part[2][o2][j]+part[3][o2][j] + bvec[oq*64+o2];
    s2 = s2 > 0.f ? s2 : 0.f;
    out[(size_t)b*NJ*CHN + j*CHN + oq*64 + o2] = s2;
  }
}

// ---------- Output head ----------
__global__ __launch_bounds__(64) void k_out(const float* __restrict__ gq, const float* __restrict__ h2,
    const float* __restrict__ Lm, const float* __restrict__ W, const float* __restrict__ bvec,
    float* __restrict__ out){
  int b = blockIdx.x, t = threadIdx.x;
  __shared__ float xs[NJ][CHN];
  __shared__ float lx[NJ][CHN];
  for (int idx=t; idx<NJ*CHN; idx+=64)
    xs[idx>>8][idx&255] = gq[(size_t)b*NJ*CHN+idx] + h2[(size_t)b*NJ*CHN+idx];
  __syncthreads();
  for (int idx=t; idx<NJ*CHN; idx+=64){
    int j = idx>>8, c = idx&255;
    float s = 0.f;
    #pragma unroll
    for (int m=0;m<NJ;m++) s += Lm[j*NJ+m]*xs[m][c];
    lx[j][c] = s;
  }
  __syncthreads();
  if (t < 63){
    int j = t/3, o = t%3;
    float acc = bvec[o];
    const float* W0 = W;
    const float* W1 = W + CHN*3;
    for (int c=0;c<CHN;c++){
      acc += xs[j][c]*W0[c*3+o];
      acc += lx[j][c]*W1[c*3+o];
    }
    out[(size_t)b*63 + t] = acc;
  }
}

extern "C" void kernel_launch(void* const* d_in, const int* in_sizes, int n_in,
                              void* d_out, int out_size, void* d_ws, size_t ws_size,
                              hipStream_t stream){
  const float* feat  = (const float*)d_in[0];
  const float* targ  = (const float*)d_in[1];
  const float* adj   = (const float*)d_in[2];
  const float* gamma = (const float*)d_in[3];
  const float* beta  = (const float*)d_in[4];
  const float* wx    = (const float*)d_in[5];
  const float* wh    = (const float*)d_in[6];
  const float* bx    = (const float*)d_in[7];
  const float* bh    = (const float*)d_in[8];
  const float* wg1   = (const float*)d_in[9];
  const float* bg1   = (const float*)d_in[10];
  const float* wg2   = (const float*)d_in[11];
  const float* bg2   = (const float*)d_in[12];
  const float* wout  = (const float*)d_in[13];
  const float* bout  = (const float*)d_in[14];

  float* ws   = (float*)d_ws;
  float* q     = ws + 0;          // 344064
  float* stats = ws + 344064;     // 64
  float* Lw    = ws + 344128;     // 448
  float* xgw   = ws + 344576;     // 1032192
  float* gout  = ws + 1376768;    // 344064
  float* h1    = ws + 1720832;    // 344064 (whp overlaps: pack->gru lifetime ends before cheb1 writes h1)
  float* h2b   = ws + 2064896;    // 344064
  unsigned* whp = (unsigned*)h1;  // 98304 uints = 384 KB

  k_lap  <<<1,    64, 0, stream>>>(adj, Lw);
  k_pack <<<384, 256, 0, stream>>>(wh, whp);
  k_corr <<<1024,256, 0, stream>>>(targ, feat, q);
  k_stats<<<21,  256, 0, stream>>>(q, stats);
  k_xg   <<<192, 256, 0, stream>>>(q, stats, gamma, beta, wx, bx, xgw);
  k_gru  <<<64,  768, 0, stream>>>(whp, bh, xgw, gout);
  k_cheb <<<256, 256, 0, stream>>>(gout, Lw, wg1, bg1, h1);
  k_cheb <<<256, 256, 0, stream>>>(h1,   Lw, wg2, bg2, h2b);
  k_out  <<<64,   64, 0, stream>>>(gout, h2b, Lw, wout, bout, (float*)d_out);
}

// Round 4
// 262.091 us; speedup vs baseline: 3.4564x; 1.5003x over previous
//
#include <hip/hip_runtime.h>
#include <cstdint>

#define B   64
#define NJ  21
#define CHN 256
#define HW  4096
#define G3  768
#define KSTEP 64

typedef _Float16 f16x8 __attribute__((ext_vector_type(8)));
typedef float    f32x4 __attribute__((ext_vector_type(4)));
typedef _Float16 f16x2 __attribute__((ext_vector_type(2)));
typedef __fp16   fp16x2v __attribute__((ext_vector_type(2)));
union PKU { fp16x2v h; unsigned u; };
union HU { unsigned u; f16x2 h; };

static __device__ inline unsigned pack_f16(float a, float b){
  HU u; u.h.x = (_Float16)a; u.h.y = (_Float16)b; return u.u;
}

// ---------- Laplacian: L = I - D^-1/2 A D^-1/2 ----------
__global__ __launch_bounds__(64) void k_lap(const float* __restrict__ adj, float* __restrict__ L){
  __shared__ float dinv[NJ];
  int t = threadIdx.x;
  if (t < NJ){
    float s = 0.f;
    for (int j=0;j<NJ;j++) s += adj[t*NJ+j];
    dinv[t] = s > 0.f ? 1.f/sqrtf(s) : 0.f;
  }
  __syncthreads();
  for (int idx=t; idx<NJ*NJ; idx+=64){
    int i = idx/NJ, j = idx%NJ;
    L[idx] = (i==j ? 1.f : 0.f) - dinv[i]*adj[idx]*dinv[j];
  }
}

// ---------- Correlation as f16 MFMA GEMM: q[b,j,c] = sum_p T[b,j,p]*F[b,c,p] ----------
// grid 512 = kb(2) x b(64) x nb(4). Block: 256 thr = 4 waves; wave w owns cols [nb*64+w*16, +16).
// Per K-step(64): reg-stage f32 -> cvt_pkrtz f16 -> XOR-swizzled LDS; 1 barrier/step; prefetch next.
__global__ __launch_bounds__(256,2) void k_corr2(const float* __restrict__ T,
    const float* __restrict__ F, _Float16* __restrict__ P){
  int bid = blockIdx.x;
  int nb = bid & 3, b = (bid>>2)&63, kb = bid>>8;
  int t = threadIdx.x;
  int w = t>>6, l = t&63;
  __shared__ __align__(16) unsigned short At[2][32*KSTEP];   // 32 x 64 f16, swizzled
  __shared__ __align__(16) unsigned short Bt[2][64*KSTEP];   // 64 x 64 f16, swizzled

  // zero A-tile rows 21..31 (both buffers) once; stays zero (never re-staged)
  for (int i=t; i<704; i+=256){
    int bi = (i>=352) ? 1 : 0; int r2 = i - bi*352;
    int r = 21 + (r2>>5); int kk = r2 & 31;
    *(unsigned*)((char*)&At[bi][0] + r*128 + kk*4) = 0u;
  }

  // staging roles: t<128 -> F rows (2 thr/row), t in [128,170) -> T rows
  bool isF = (t < 128);
  bool isT = (t >= 128) && (t < 170);
  const float4* gp = nullptr; int srow = 0, shalf = 0;
  if (isF){
    srow = t>>1; shalf = t&1;
    gp = (const float4*)(F + ((size_t)b*CHN + nb*64 + srow)*HW + (size_t)kb*2048) + shalf*8;
  } else if (isT){
    int tt = t-128; srow = tt>>1; shalf = tt&1;
    gp = (const float4*)(T + ((size_t)b*NJ + srow)*HW + (size_t)kb*2048) + shalf*8;
  }
  float4 ld[8];
  if (gp){
    #pragma unroll
    for (int i=0;i<8;i++) ld[i] = gp[i];
  }

  f32x4 acc0 = {0.f,0.f,0.f,0.f}, acc1 = {0.f,0.f,0.f,0.f};
  int arow0 = (l&15);            // A row (m) low frag
  int brow  = w*16 + (l&15);     // B-tile row = col within block
  int kbyt  = (l>>4)*16;         // k-slice byte offset within 32-k chunk

  for (int s=0; s<32; ++s){
    int bi = s & 1;
    if (gp){
      unsigned short* tile = isF ? &Bt[bi][0] : &At[bi][0];
      #pragma unroll
      for (int i=0;i<8;i++){
        PKU p0, p1;
        p0.h = __builtin_amdgcn_cvt_pkrtz(ld[i].x, ld[i].y);
        p1.h = __builtin_amdgcn_cvt_pkrtz(ld[i].z, ld[i].w);
        int addr = (srow*128 + shalf*64 + i*8) ^ ((srow&7)<<4);
        uint2 v; v.x = p0.u; v.y = p1.u;
        *(uint2*)((char*)tile + addr) = v;
      }
      if (s < 31){
        const float4* gn = gp + (size_t)(s+1)*16;
        #pragma unroll
        for (int i=0;i<8;i++) ld[i] = gn[i];   // prefetch next step (reg-dest, survives barrier)
      }
    }
    __syncthreads();
    #pragma unroll
    for (int kc=0;kc<2;kc++){
      int kb2 = kc*64 + kbyt;
      int ab0 = ((arow0)*128      + kb2) ^ ((arow0&7)<<4);
      int ab1 = ((arow0+16)*128   + kb2) ^ ((arow0&7)<<4);
      int bb  = ((brow)*128       + kb2) ^ ((brow&7)<<4);
      f16x8 a0 = *(const f16x8*)((const char*)&At[bi][0] + ab0);
      f16x8 a1 = *(const f16x8*)((const char*)&At[bi][0] + ab1);
      f16x8 bf = *(const f16x8*)((const char*)&Bt[bi][0] + bb);
      acc0 = __builtin_amdgcn_mfma_f32_16x16x32_f16(a0, bf, acc0, 0, 0, 0);
      acc1 = __builtin_amdgcn_mfma_f32_16x16x32_f16(a1, bf, acc1, 0, 0, 0);
    }
    __syncthreads();
  }

  // write f16 partials: P[kb][b][row][col]
  int cbase = nb*64 + w*16 + (l&15);
  #pragma unroll
  for (int r=0;r<4;r++){
    int row0 = (l>>4)*4 + r;
    if (row0 < 21)
      P[(((size_t)kb*64 + b)*21 + row0)*256 + cbase] = (_Float16)acc0[r];
    int row1 = row0 + 16;
    if (row1 < 21)
      P[(((size_t)kb*64 + b)*21 + row1)*256 + cbase] = (_Float16)acc1[r];
  }
}

// ---------- BN stats per joint; also reduces the 2 k-partials into f32 q ----------
__global__ __launch_bounds__(256) void k_stats(const _Float16* __restrict__ P,
    float* __restrict__ q, float* __restrict__ stats){
  int j = blockIdx.x, t = threadIdx.x;
  float s = 0.f, ss = 0.f;
  for (int b=0;b<B;b++){
    size_t i0 = ((size_t)b*21 + j)*256 + t;
    float v = (float)P[i0] + (float)P[(size_t)64*21*256 + i0];
    q[((size_t)b*NJ + j)*CHN + t] = v;
    s += v; ss += v*v;
  }
  #pragma unroll
  for (int o=32;o>0;o>>=1){ s += __shfl_down(s,o); ss += __shfl_down(ss,o); }
  __shared__ float sb[4], ssb[4];
  int wid = t>>6;
  if ((t&63)==0){ sb[wid]=s; ssb[wid]=ss; }
  __syncthreads();
  if (t==0){
    float S  = sb[0]+sb[1]+sb[2]+sb[3];
    float SS = ssb[0]+ssb[1]+ssb[2]+ssb[3];
    float mean = S * (1.f/16384.f);
    float var  = SS * (1.f/16384.f) - mean*mean;
    stats[j]      = mean;
    stats[NJ + j] = 1.f/sqrtf(var + 1e-5f);
  }
}

// ---------- BN apply + LeakyReLU + xg = xn @ wx + bx ----------
__global__ __launch_bounds__(256) void k_xg(const float* __restrict__ q,
    const float* __restrict__ stats, const float* __restrict__ gamma, const float* __restrict__ beta,
    const float* __restrict__ wx, const float* __restrict__ bx, float* __restrict__ xg){
  int b = blockIdx.x/3, sl = blockIdx.x%3;
  int t = threadIdx.x;
  int col = sl*256 + t;
  __shared__ float xn[NJ][CHN];
  for (int idx=t; idx<NJ*CHN; idx+=256){
    int j = idx >> 8;
    float v = (q[(size_t)b*NJ*CHN + idx] - stats[j]) * stats[NJ+j];
    v = v * gamma[j] + beta[j];
    xn[j][idx & 255] = v > 0.f ? v : 0.1f*v;
  }
  __syncthreads();
  float acc[NJ];
  #pragma unroll
  for (int j=0;j<NJ;j++) acc[j]=0.f;
  for (int c=0;c<CHN;c++){
    float wv = wx[(size_t)c*G3 + col];
    #pragma unroll
    for (int j=0;j<NJ;j++) acc[j] += xn[j][c]*wv;
  }
  float bv = bx[col];
  #pragma unroll
  for (int j=0;j<NJ;j++) xg[((size_t)b*NJ+j)*G3 + col] = acc[j] + bv;
}

// ---------- pack wh to f16 pairs ----------
__global__ __launch_bounds__(256) void k_pack(const float* __restrict__ wh, unsigned* __restrict__ whp){
  int idx = blockIdx.x*256 + threadIdx.x;
  int c2 = idx / G3, col = idx % G3;
  float w0 = wh[(size_t)(2*c2)*G3 + col];
  float w1 = wh[(size_t)(2*c2+1)*G3 + col];
  whp[idx] = pack_f16(w0, w1);
}

// ---------- GRU: one block per batch ----------
__global__ __launch_bounds__(768,3) void k_gru(const unsigned* __restrict__ whp,
    const float* __restrict__ bh, const float* __restrict__ xg, float* __restrict__ gout){
  int b = blockIdx.x;
  int col = threadIdx.x;
  int l = col & 63;
  __shared__ float hf[256];
  __shared__ float lr[256], lz[256];
  float bhv = bh[col];
  if (col < 256) hf[col] = 0.f;
  unsigned hv0 = 0u, hv1 = 0u;
  float xv_next = xg[((size_t)b*NJ + 0)*G3 + col];
  __syncthreads();
  for (int step=0; step<NJ; ++step){
    float xvc = xv_next;
    if (step < NJ-1) xv_next = xg[((size_t)b*NJ + step+1)*G3 + col];
    float a0 = 0.f, a1 = 0.f;
    #pragma unroll
    for (int c2=0; c2<64; ++c2){
      HU w; w.u = whp[c2*G3 + col];
      HU h; h.u = __builtin_amdgcn_readlane(hv0, c2);
#if __has_builtin(__builtin_amdgcn_fdot2)
      a0 = __builtin_amdgcn_fdot2(w.h, h.h, a0, false);
#else
      a0 += (float)w.h.x*(float)h.h.x + (float)w.h.y*(float)h.h.y;
#endif
    }
    #pragma unroll
    for (int c2=0; c2<64; ++c2){
      HU w; w.u = whp[(64+c2)*G3 + col];
      HU h; h.u = __builtin_amdgcn_readlane(hv1, c2);
#if __has_builtin(__builtin_amdgcn_fdot2)
      a1 = __builtin_amdgcn_fdot2(w.h, h.h, a1, false);
#else
      a1 += (float)w.h.x*(float)h.h.x + (float)w.h.y*(float)h.h.y;
#endif
    }
    float a = a0 + a1 + bhv;
    if (col < 256)      lr[col]     = 1.f/(1.f+__expf(-(xvc + a)));
    else if (col < 512) lz[col-256] = 1.f/(1.f+__expf(-(xvc + a)));
    __syncthreads();
    if (col >= 512){
      int i = col - 512;
      float nv = tanhf(xvc + lr[i]*a);
      float z  = lz[i];
      float hnew = (1.f - z)*nv + z*hf[i];
      gout[((size_t)b*NJ + step)*CHN + i] = hnew;
      hf[i] = hnew;
    }
    __syncthreads();
    float2 p0 = *(const float2*)&hf[2*l];
    float2 p1 = *(const float2*)&hf[128 + 2*l];
    hv0 = pack_f16(p0.x, p0.y);
    hv1 = pack_f16(p1.x, p1.y);
  }
}

// ---------- ChebConv K=2 + bias + ReLU ----------
__global__ __launch_bounds__(256) void k_cheb(const float* __restrict__ xin,
    const float* __restrict__ Lm, const float* __restrict__ W,
    const float* __restrict__ bvec, float* __restrict__ out){
  int b = blockIdx.x >> 2, oq = blockIdx.x & 3;
  int t = threadIdx.x;
  int ol = t & 63, ck = t >> 6;
  __shared__ float xs[NJ][CHN];
  __shared__ float lx[NJ][CHN];
  __shared__ float part[4][64][NJ];
  for (int idx=t; idx<NJ*CHN; idx+=256) xs[idx>>8][idx&255] = xin[(size_t)b*NJ*CHN + idx];
  __syncthreads();
  for (int idx=t; idx<NJ*CHN; idx+=256){
    int j = idx>>8, c = idx&255;
    float sacc = 0.f;
    #pragma unroll
    for (int m=0;m<NJ;m++) sacc += Lm[j*NJ+m]*xs[m][c];
    lx[j][c] = sacc;
  }
  __syncthreads();
  int o = oq*64 + ol;
  float acc[NJ];
  #pragma unroll
  for (int j=0;j<NJ;j++) acc[j]=0.f;
  const float* W0 = W;
  const float* W1 = W + CHN*CHN;
  for (int cc=0; cc<64; ++cc){
    int c = ck*64 + cc;
    float w0 = W0[(size_t)c*CHN + o];
    float w1 = W1[(size_t)c*CHN + o];
    #pragma unroll
    for (int j=0;j<NJ;j++){ acc[j] += xs[j][c]*w0; acc[j] += lx[j][c]*w1; }
  }
  #pragma unroll
  for (int j=0;j<NJ;j++) part[ck][ol][j] = acc[j];
  __syncthreads();
  for (int idx=t; idx<64*NJ; idx+=256){
    int o2 = idx & 63, j = idx >> 6;
    float s2 = part[0][o2][j]+part[1][o2][j]+part[2][o2][j]+part[3][o2][j] + bvec[oq*64+o2];
    s2 = s2 > 0.f ? s2 : 0.f;
    out[(size_t)b*NJ*CHN + j*CHN + oq*64 + o2] = s2;
  }
}

// ---------- Output head ----------
__global__ __launch_bounds__(64) void k_out(const float* __restrict__ gq, const float* __restrict__ h2,
    const float* __restrict__ Lm, const float* __restrict__ W, const float* __restrict__ bvec,
    float* __restrict__ out){
  int b = blockIdx.x, t = threadIdx.x;
  __shared__ float xs[NJ][CHN];
  __shared__ float lx[NJ][CHN];
  for (int idx=t; idx<NJ*CHN; idx+=64)
    xs[idx>>8][idx&255] = gq[(size_t)b*NJ*CHN+idx] + h2[(size_t)b*NJ*CHN+idx];
  __syncthreads();
  for (int idx=t; idx<NJ*CHN; idx+=64){
    int j = idx>>8, c = idx&255;
    float s = 0.f;
    #pragma unroll
    for (int m=0;m<NJ;m++) s += Lm[j*NJ+m]*xs[m][c];
    lx[j][c] = s;
  }
  __syncthreads();
  if (t < 63){
    int j = t/3, o = t%3;
    float acc = bvec[o];
    const float* W0 = W;
    const float* W1 = W + CHN*3;
    for (int c=0;c<CHN;c++){
      acc += xs[j][c]*W0[c*3+o];
      acc += lx[j][c]*W1[c*3+o];
    }
    out[(size_t)b*63 + t] = acc;
  }
}

extern "C" void kernel_launch(void* const* d_in, const int* in_sizes, int n_in,
                              void* d_out, int out_size, void* d_ws, size_t ws_size,
                              hipStream_t stream){
  const float* feat  = (const float*)d_in[0];
  const float* targ  = (const float*)d_in[1];
  const float* adj   = (const float*)d_in[2];
  const float* gamma = (const float*)d_in[3];
  const float* beta  = (const float*)d_in[4];
  const float* wx    = (const float*)d_in[5];
  const float* wh    = (const float*)d_in[6];
  const float* bx    = (const float*)d_in[7];
  const float* bh    = (const float*)d_in[8];
  const float* wg1   = (const float*)d_in[9];
  const float* bg1   = (const float*)d_in[10];
  const float* wg2   = (const float*)d_in[11];
  const float* bg2   = (const float*)d_in[12];
  const float* wout  = (const float*)d_in[13];
  const float* bout  = (const float*)d_in[14];

  float* ws   = (float*)d_ws;
  float* q     = ws + 0;          // 344064 f32
  float* stats = ws + 344064;     // 64
  float* Lw    = ws + 344128;     // 448
  float* xgw   = ws + 344576;     // 1032192 f32
  float* gout  = ws + 1376768;    // 344064
  float* h1    = ws + 1720832;    // 344064
  float* h2b   = ws + 2064896;    // 344064
  // P (f16 k-partials, 2x64x21x256 = 2752512 ushorts = 5505024 B) overlaps xgw+gout exactly;
  // dead after k_stats, before k_xg/k_gru write those regions.
  _Float16* P = (_Float16*)(ws + 344576);
  unsigned* whp = (unsigned*)h1;  // dead before k_cheb writes h1

  k_lap  <<<1,    64, 0, stream>>>(adj, Lw);
  k_pack <<<384, 256, 0, stream>>>(wh, whp);
  k_corr2<<<512, 256, 0, stream>>>(targ, feat, P);
  k_stats<<<21,  256, 0, stream>>>(P, q, stats);
  k_xg   <<<192, 256, 0, stream>>>(q, stats, gamma, beta, wx, bx, xgw);
  k_gru  <<<64,  768, 0, stream>>>(whp, bh, xgw, gout);
  k_cheb <<<256, 256, 0, stream>>>(gout, Lw, wg1, bg1, h1);
  k_cheb <<<256, 256, 0, stream>>>(h1,   Lw, wg2, bg2, h2b);
  k_out  <<<64,   64, 0, stream>>>(gout, h2b, Lw, wout, bout, (float*)d_out);
}